// Round 4
// baseline (164.549 us; speedup 1.0000x reference)
//
#include <hip/hip_runtime.h>

#define GAMMA 0.99f
#define LAM   0.95f

typedef float v4f __attribute__((ext_vector_type(4)));
typedef int   v4i __attribute__((ext_vector_type(4)));

constexpr int LCHUNK = 32;             // timesteps per lane; requires T == 64*LCHUNK
constexpr int WPB    = 4;              // independent rows (waves) per block

// One WAVE per row. Lane i owns columns [i*32, i*32+32). No __syncthreads, no LDS.
// Backward linear recurrence g[t] = delta[t] + c[t]*g[t+1] parallelized via
// affine composition (a, m) per lane + 64-lane shuffle suffix-scan.
__global__ __launch_bounds__(256, 4) void gae_wave_kernel(
    const float* __restrict__ rewards,
    const float* __restrict__ values,
    const float* __restrict__ next_value,
    const int*   __restrict__ done,
    float* __restrict__ adv_out,
    float* __restrict__ ret_out,
    int B, int T)
{
    const int tid  = threadIdx.x;
    const int lane = tid & 63;
    const int wave = tid >> 6;
    const int row  = blockIdx.x * WPB + wave;
    if (row >= B) return;

    const long rowbase = (long)row * T;
    const int  col0    = lane * LCHUNK;

    // ---- issue ALL loads up front: 24 KiB in flight per wave ----
    float rr[LCHUNK], vv[LCHUNK];
    int   dd[LCHUNK];
    {
        const v4f* gr = reinterpret_cast<const v4f*>(rewards + rowbase + col0);
        const v4f* gv = reinterpret_cast<const v4f*>(values  + rowbase + col0);
        const v4i* gd = reinterpret_cast<const v4i*>(done    + rowbase + col0);
        v4f* R4 = reinterpret_cast<v4f*>(rr);
        v4f* V4 = reinterpret_cast<v4f*>(vv);
        v4i* D4 = reinterpret_cast<v4i*>(dd);
#pragma unroll
        for (int k = 0; k < LCHUNK / 4; ++k) R4[k] = gr[k];
#pragma unroll
        for (int k = 0; k < LCHUNK / 4; ++k) V4[k] = gv[k];
#pragma unroll
        for (int k = 0; k < LCHUNK / 4; ++k) D4[k] = gd[k];
    }
    const float nvrow = next_value[row];   // wave-uniform broadcast load

    // ---- +1-shifted boundary via neighbor lane (lane 63 IS the row end) ----
    int   dnext = __shfl_down(dd[0], 1);   // done[col0+32]
    float vnext = __shfl_down(vv[0], 1);   // values[col0+32]
    if (lane == 63) {
        dnext = dd[LCHUNK - 1];            // dcol clamps to T-1
        vnext = nvrow;                     // bootstrap value
    }

    // ---- pack done[col0+1 .. col0+32] into a 32-bit mask ----
    unsigned mask = 0;
#pragma unroll
    for (int j = 0; j < LCHUNK - 1; ++j)
        mask |= (dd[j + 1] ? 1u : 0u) << j;
    mask |= (dnext ? 1u : 0u) << (LCHUNK - 1);

    // ---- delta[t] (kept in regs; rr dies here) ----
    float delta[LCHUNK];
#pragma unroll
    for (int j = 0; j < LCHUNK; ++j) {
        const float nnt = ((mask >> j) & 1u) ? 0.0f : 1.0f;
        const float nv  = (j < LCHUNK - 1) ? vv[j + 1] : vnext;
        delta[j] = rr[j] + GAMMA * nv * nnt - vv[j];
    }

    // ---- per-lane affine composition over the chunk (backward) ----
    float a = 0.0f, m = 1.0f;
#pragma unroll
    for (int j = LCHUNK - 1; j >= 0; --j) {
        const float c = ((mask >> j) & 1u) ? 0.0f : (GAMMA * LAM);
        a = delta[j] + c * a;
        m = c * m;
    }

    // ---- 64-lane inclusive SUFFIX scan of affine fns ----
    float sa = a, sm = m;
#pragma unroll
    for (int d = 1; d < 64; d <<= 1) {
        float oa = __shfl_down(sa, d);
        float om = __shfl_down(sm, d);
        if (lane + d < 64) { sa = sa + sm * oa; sm = sm * om; }
    }
    // exclusive suffix applied to g_incoming = 0 (end of row): gin = ea
    float gin = __shfl_down(sa, 1);
    if (lane == 63) gin = 0.0f;

    // ---- replay: exact sequential recurrence; adv overwrites delta ----
#pragma unroll
    for (int j = LCHUNK - 1; j >= 0; --j) {
        const float c = ((mask >> j) & 1u) ? 0.0f : (GAMMA * LAM);
        gin = delta[j] + c * gin;
        delta[j] = gin;                    // delta[] now holds advantages
    }

    // ---- plain vectorized stores (nt stores inflated WRITE_SIZE — reverted) ----
    v4f* a4 = reinterpret_cast<v4f*>(adv_out + rowbase + col0);
    v4f* t4 = reinterpret_cast<v4f*>(ret_out + rowbase + col0);
    const v4f* A4 = reinterpret_cast<const v4f*>(delta);
#pragma unroll
    for (int k = 0; k < LCHUNK / 4; ++k) a4[k] = A4[k];
#pragma unroll
    for (int k = 0; k < LCHUNK / 4; ++k) {
        v4f s;
        s.x = delta[4 * k + 0] + vv[4 * k + 0];
        s.y = delta[4 * k + 1] + vv[4 * k + 1];
        s.z = delta[4 * k + 2] + vv[4 * k + 2];
        s.w = delta[4 * k + 3] + vv[4 * k + 3];
        t4[k] = s;
    }
}

// Fallback for shapes where T != 64*LCHUNK: one thread per row, sequential.
__global__ void gae_naive_kernel(
    const float* __restrict__ rewards,
    const float* __restrict__ values,
    const float* __restrict__ next_value,
    const int*   __restrict__ done,
    float* __restrict__ adv_out,
    float* __restrict__ ret_out,
    int B, int T)
{
    int row = blockIdx.x * blockDim.x + threadIdx.x;
    if (row >= B) return;
    long base = (long)row * T;
    float g = 0.0f;
    for (int t = T - 1; t >= 0; --t) {
        int dcol = (t + 1 < T) ? (t + 1) : (T - 1);
        float nnt = 1.0f - (float)done[base + dcol];
        float nv  = (t + 1 < T) ? values[base + t + 1] : next_value[row];
        float dl  = rewards[base + t] + GAMMA * nv * nnt - values[base + t];
        g = dl + (GAMMA * LAM) * nnt * g;
        adv_out[base + t] = g;
        ret_out[base + t] = g + values[base + t];
    }
}

extern "C" void kernel_launch(void* const* d_in, const int* in_sizes, int n_in,
                              void* d_out, int out_size, void* d_ws, size_t ws_size,
                              hipStream_t stream) {
    const float* rewards    = (const float*)d_in[0];
    const float* values     = (const float*)d_in[1];
    const float* next_value = (const float*)d_in[2];
    const int*   done       = (const int*)d_in[3];

    const int B = in_sizes[2];               // next_value is [B]
    const int T = in_sizes[0] / B;           // rewards is [B, T]

    float* adv = (float*)d_out;
    float* ret = adv + (long)B * T;

    if (T == 64 * LCHUNK) {
        const int grid = (B + WPB - 1) / WPB;
        gae_wave_kernel<<<grid, 256, 0, stream>>>(
            rewards, values, next_value, done, adv, ret, B, T);
    } else {
        gae_naive_kernel<<<(B + 255) / 256, 256, 0, stream>>>(
            rewards, values, next_value, done, adv, ret, B, T);
    }
}

// Round 5
// 153.176 us; speedup vs baseline: 1.0742x; 1.0742x over previous
//
#include <hip/hip_runtime.h>

#define GAMMA 0.99f
#define LAM   0.95f

typedef float v4f __attribute__((ext_vector_type(4)));
typedef int   v4i __attribute__((ext_vector_type(4)));

constexpr int CH   = 8;      // columns per lane per segment (32 B — proven layout)
constexpr int SEG  = 64 * CH; // 512 columns per segment
constexpr int NSEG = 4;      // segments per row; requires T == 2048
constexpr int WPB  = 4;      // waves (rows) per 256-thread block

struct Raw {                  // one segment's raw loads for one lane (24 VGPRs)
    v4f ra, rb, va, vb;
    v4i da, db;
};

__device__ __forceinline__ Raw load_seg(const float* __restrict__ r,
                                        const float* __restrict__ v,
                                        const int*   __restrict__ d,
                                        long base) {
    Raw x;
    x.ra = reinterpret_cast<const v4f*>(r + base)[0];
    x.rb = reinterpret_cast<const v4f*>(r + base)[1];
    x.va = reinterpret_cast<const v4f*>(v + base)[0];
    x.vb = reinterpret_cast<const v4f*>(v + base)[1];
    x.da = reinterpret_cast<const v4i*>(d + base)[0];
    x.db = reinterpret_cast<const v4i*>(d + base)[1];
    return x;
}

// Process one 512-col segment for one wave. No LDS, no barriers:
// cross-lane via shfl only. g / bv / bd carry state to the next (left) segment.
__device__ __forceinline__ void compute_seg(
    const Raw x, const int lane, const bool last_seg, const float nvrow,
    float& g, float& bv, int& bd,
    float* __restrict__ adv_out, float* __restrict__ ret_out, const long base)
{
    float r[CH] = {x.ra.x, x.ra.y, x.ra.z, x.ra.w, x.rb.x, x.rb.y, x.rb.z, x.rb.w};
    float v[CH] = {x.va.x, x.va.y, x.va.z, x.va.w, x.vb.x, x.vb.y, x.vb.z, x.vb.w};
    int   d[CH] = {x.da.x, x.da.y, x.da.z, x.da.w, x.db.x, x.db.y, x.db.z, x.db.w};

    // +1-shifted boundary: next lane's first element; lane 63 uses the
    // carry-in boundary (first element of the segment to our right), or
    // clamp/bootstrap at the true row end.
    int   dnext = __shfl_down(d[0], 1);
    float vnext = __shfl_down(v[0], 1);
    if (lane == 63) {
        dnext = last_seg ? d[CH - 1] : bd;   // done clamps to T-1 at row end
        vnext = last_seg ? nvrow     : bv;   // bootstrap next_value at row end
    }
    // boundary for the segment processed after this one (to our left)
    const float bv_new = __shfl(v[0], 0);
    const int   bd_new = __shfl(d[0], 0);

    // delta[t], c[t]
    float delta[CH], c[CH];
#pragma unroll
    for (int j = 0; j < CH; ++j) {
        const int   dn  = (j < CH - 1) ? d[j + 1] : dnext;
        const float nv  = (j < CH - 1) ? v[j + 1] : vnext;
        const float nnt = dn ? 0.0f : 1.0f;
        delta[j] = r[j] + GAMMA * nv * nnt - v[j];
        c[j]     = dn ? 0.0f : (GAMMA * LAM);
    }

    // per-lane backward affine composition: g_at_chunk_start = a + m * g_in
    float a = 0.0f, m = 1.0f;
#pragma unroll
    for (int j = CH - 1; j >= 0; --j) { a = delta[j] + c[j] * a; m = c[j] * m; }

    // 64-lane inclusive suffix scan of affine functions
    float sa = a, sm = m;
#pragma unroll
    for (int s = 1; s < 64; s <<= 1) {
        const float oa = __shfl_down(sa, s);
        const float om = __shfl_down(sm, s);
        if (lane + s < 64) { sa += sm * oa; sm *= om; }
    }
    // exclusive suffix (lanes > lane), then apply segment carry g
    float gin = __shfl_down(sa, 1);
    float em  = __shfl_down(sm, 1);
    if (lane == 63) { gin = 0.0f; em = 1.0f; }
    gin = gin + em * g;

    // replay: exact sequential recurrence over the chunk
    float adv[CH];
#pragma unroll
    for (int j = CH - 1; j >= 0; --j) { gin = delta[j] + c[j] * gin; adv[j] = gin; }

    // plain coalesced stores (wave covers 2 KiB contiguous per array)
    v4f* a4 = reinterpret_cast<v4f*>(adv_out + base);
    v4f* t4 = reinterpret_cast<v4f*>(ret_out + base);
    v4f o0; o0.x = adv[0]; o0.y = adv[1]; o0.z = adv[2]; o0.w = adv[3];
    v4f o1; o1.x = adv[4]; o1.y = adv[5]; o1.z = adv[6]; o1.w = adv[7];
    v4f s0; s0.x = adv[0]+v[0]; s0.y = adv[1]+v[1]; s0.z = adv[2]+v[2]; s0.w = adv[3]+v[3];
    v4f s1; s1.x = adv[4]+v[4]; s1.y = adv[5]+v[5]; s1.z = adv[6]+v[6]; s1.w = adv[7]+v[7];
    a4[0] = o0; a4[1] = o1;
    t4[0] = s0; t4[1] = s1;

    // carries for the next (left) segment
    g  = __shfl(gin, 0);          // adv at this segment's first column
    bv = bv_new;
    bd = bd_new;
}

// One WAVE per row; row walked right-to-left in NSEG segments, software-
// pipelined 2 segments deep so loads stay in flight during scan compute.
__global__ __launch_bounds__(256, 4) void gae_wave_seg_kernel(
    const float* __restrict__ rewards,
    const float* __restrict__ values,
    const float* __restrict__ next_value,
    const int*   __restrict__ done,
    float* __restrict__ adv_out,
    float* __restrict__ ret_out,
    int B, int T)
{
    const int tid  = threadIdx.x;
    const int lane = tid & 63;
    const int wave = tid >> 6;
    const int row  = blockIdx.x * WPB + wave;
    if (row >= B) return;

    const long rowbase = (long)row * T;
    const long laneoff = rowbase + lane * CH;

    // prefetch segments 3 and 2 (rightmost first)
    Raw b3 = load_seg(rewards, values, done, laneoff + 3 * SEG);
    Raw b2 = load_seg(rewards, values, done, laneoff + 2 * SEG);
    const float nvrow = next_value[row];

    float g = 0.0f, bv = 0.0f;
    int   bd = 0;

    Raw b1 = load_seg(rewards, values, done, laneoff + 1 * SEG);
    compute_seg(b3, lane, true,  nvrow, g, bv, bd, adv_out, ret_out, laneoff + 3 * SEG);
    Raw b0 = load_seg(rewards, values, done, laneoff + 0 * SEG);
    compute_seg(b2, lane, false, nvrow, g, bv, bd, adv_out, ret_out, laneoff + 2 * SEG);
    compute_seg(b1, lane, false, nvrow, g, bv, bd, adv_out, ret_out, laneoff + 1 * SEG);
    compute_seg(b0, lane, false, nvrow, g, bv, bd, adv_out, ret_out, laneoff + 0 * SEG);
}

// Fallback for shapes where T != NSEG*SEG: one thread per row, sequential.
__global__ void gae_naive_kernel(
    const float* __restrict__ rewards,
    const float* __restrict__ values,
    const float* __restrict__ next_value,
    const int*   __restrict__ done,
    float* __restrict__ adv_out,
    float* __restrict__ ret_out,
    int B, int T)
{
    int row = blockIdx.x * blockDim.x + threadIdx.x;
    if (row >= B) return;
    long base = (long)row * T;
    float g = 0.0f;
    for (int t = T - 1; t >= 0; --t) {
        int dcol = (t + 1 < T) ? (t + 1) : (T - 1);
        float nnt = 1.0f - (float)done[base + dcol];
        float nv  = (t + 1 < T) ? values[base + t + 1] : next_value[row];
        float dl  = rewards[base + t] + GAMMA * nv * nnt - values[base + t];
        g = dl + (GAMMA * LAM) * nnt * g;
        adv_out[base + t] = g;
        ret_out[base + t] = g + values[base + t];
    }
}

extern "C" void kernel_launch(void* const* d_in, const int* in_sizes, int n_in,
                              void* d_out, int out_size, void* d_ws, size_t ws_size,
                              hipStream_t stream) {
    const float* rewards    = (const float*)d_in[0];
    const float* values     = (const float*)d_in[1];
    const float* next_value = (const float*)d_in[2];
    const int*   done       = (const int*)d_in[3];

    const int B = in_sizes[2];               // next_value is [B]
    const int T = in_sizes[0] / B;           // rewards is [B, T]

    float* adv = (float*)d_out;
    float* ret = adv + (long)B * T;

    if (T == NSEG * SEG) {
        const int grid = (B + WPB - 1) / WPB;
        gae_wave_seg_kernel<<<grid, 256, 0, stream>>>(
            rewards, values, next_value, done, adv, ret, B, T);
    } else {
        gae_naive_kernel<<<(B + 255) / 256, 256, 0, stream>>>(
            rewards, values, next_value, done, adv, ret, B, T);
    }
}

// Round 6
// 149.682 us; speedup vs baseline: 1.0993x; 1.0233x over previous
//
#include <hip/hip_runtime.h>

#define GAMMA 0.99f
#define LAM   0.95f

typedef float v4f __attribute__((ext_vector_type(4)));
typedef int   v4i __attribute__((ext_vector_type(4)));

constexpr int CH   = 8;       // columns per lane per segment (32 B contiguous)
constexpr int SEG  = 64 * CH; // 512 columns per segment
constexpr int NSEG = 4;       // segments per row; requires T == 2048
constexpr int RPW  = 2;       // rows per wave (pipelined against each other)

struct Raw {                  // one segment's raw loads for one lane (24 VGPRs)
    v4f ra, rb, va, vb;
    v4i da, db;
};

struct RowState {             // carry across segments of one row
    float g;   // GAE entering from the right
    float bv;  // values[] first element of segment to the right
    int   bd;  // done[] first element of segment to the right
};

__device__ __forceinline__ Raw load_seg(const float* __restrict__ r,
                                        const float* __restrict__ v,
                                        const int*   __restrict__ d,
                                        long base) {
    Raw x;
    x.ra = reinterpret_cast<const v4f*>(r + base)[0];
    x.rb = reinterpret_cast<const v4f*>(r + base)[1];
    x.va = reinterpret_cast<const v4f*>(v + base)[0];
    x.vb = reinterpret_cast<const v4f*>(v + base)[1];
    x.da = reinterpret_cast<const v4i*>(d + base)[0];
    x.db = reinterpret_cast<const v4i*>(d + base)[1];
    return x;
}

// Process one 512-col segment for one wave-row. No LDS, no barriers.
__device__ __forceinline__ void compute_seg(
    const Raw x, const int lane, const bool last_seg, const float nvrow,
    RowState& st,
    float* __restrict__ adv_out, float* __restrict__ ret_out, const long base)
{
    float r[CH] = {x.ra.x, x.ra.y, x.ra.z, x.ra.w, x.rb.x, x.rb.y, x.rb.z, x.rb.w};
    float v[CH] = {x.va.x, x.va.y, x.va.z, x.va.w, x.vb.x, x.vb.y, x.vb.z, x.vb.w};
    int   d[CH] = {x.da.x, x.da.y, x.da.z, x.da.w, x.db.x, x.db.y, x.db.z, x.db.w};

    // +1-shifted boundary: next lane's first element; lane 63 uses carry-in
    // boundary, or clamp/bootstrap at the true row end.
    int   dnext = __shfl_down(d[0], 1);
    float vnext = __shfl_down(v[0], 1);
    if (lane == 63) {
        dnext = last_seg ? d[CH - 1] : st.bd;   // done clamps to T-1 at row end
        vnext = last_seg ? nvrow     : st.bv;   // bootstrap next_value at row end
    }
    const float bv_new = __shfl(v[0], 0);
    const int   bd_new = __shfl(d[0], 0);

    float delta[CH], c[CH];
#pragma unroll
    for (int j = 0; j < CH; ++j) {
        const int   dn  = (j < CH - 1) ? d[j + 1] : dnext;
        const float nv  = (j < CH - 1) ? v[j + 1] : vnext;
        const float nnt = dn ? 0.0f : 1.0f;
        delta[j] = r[j] + GAMMA * nv * nnt - v[j];
        c[j]     = dn ? 0.0f : (GAMMA * LAM);
    }

    // per-lane backward affine composition: g_at_chunk_start = a + m * g_in
    float a = 0.0f, m = 1.0f;
#pragma unroll
    for (int j = CH - 1; j >= 0; --j) { a = delta[j] + c[j] * a; m = c[j] * m; }

    // 64-lane inclusive suffix scan of affine functions
    float sa = a, sm = m;
#pragma unroll
    for (int s = 1; s < 64; s <<= 1) {
        const float oa = __shfl_down(sa, s);
        const float om = __shfl_down(sm, s);
        if (lane + s < 64) { sa += sm * oa; sm *= om; }
    }
    float gin = __shfl_down(sa, 1);
    float em  = __shfl_down(sm, 1);
    if (lane == 63) { gin = 0.0f; em = 1.0f; }
    gin = gin + em * st.g;

    // replay: exact sequential recurrence over the chunk
    float adv[CH];
#pragma unroll
    for (int j = CH - 1; j >= 0; --j) { gin = delta[j] + c[j] * gin; adv[j] = gin; }

    // plain coalesced stores (wave covers 2 KiB contiguous per array)
    v4f* a4 = reinterpret_cast<v4f*>(adv_out + base);
    v4f* t4 = reinterpret_cast<v4f*>(ret_out + base);
    v4f o0; o0.x = adv[0]; o0.y = adv[1]; o0.z = adv[2]; o0.w = adv[3];
    v4f o1; o1.x = adv[4]; o1.y = adv[5]; o1.z = adv[6]; o1.w = adv[7];
    v4f s0; s0.x = adv[0]+v[0]; s0.y = adv[1]+v[1]; s0.z = adv[2]+v[2]; s0.w = adv[3]+v[3];
    v4f s1; s1.x = adv[4]+v[4]; s1.y = adv[5]+v[5]; s1.z = adv[6]+v[6]; s1.w = adv[7]+v[7];
    a4[0] = o0; a4[1] = o1;
    t4[0] = s0; t4[1] = s1;

    st.g  = __shfl(gin, 0);   // adv at this segment's first column
    st.bv = bv_new;
    st.bd = bd_new;
}

// One wave : TWO rows, segment-pipelined and cross-row interleaved so load
// issue is spread through the wave's lifetime and two independent shfl
// chains co-schedule. No LDS, no barriers.
__global__ __launch_bounds__(256, 2) void gae_wave2_kernel(
    const float* __restrict__ rewards,
    const float* __restrict__ values,
    const float* __restrict__ next_value,
    const int*   __restrict__ done,
    float* __restrict__ adv_out,
    float* __restrict__ ret_out,
    int B, int T)
{
    const int tid  = threadIdx.x;
    const int lane = tid & 63;
    const int wave = tid >> 6;
    const int gw   = blockIdx.x * 4 + wave;     // global wave id
    const int row0 = gw * RPW;
    const int row1 = row0 + 1;
    if (row0 >= B) return;
    const bool has1 = (row1 < B);

    const long off0 = (long)row0 * T + lane * CH;
    const long off1 = (long)row1 * T + lane * CH;

    // prime: rightmost segments of both rows (depth-2 per row)
    Raw a3 = load_seg(rewards, values, done, off0 + 3 * SEG);
    Raw b3 = has1 ? load_seg(rewards, values, done, off1 + 3 * SEG) : Raw{};
    Raw a2 = load_seg(rewards, values, done, off0 + 2 * SEG);
    Raw b2 = has1 ? load_seg(rewards, values, done, off1 + 2 * SEG) : Raw{};
    const float nv0 = next_value[row0];
    const float nv1 = has1 ? next_value[row1] : 0.0f;

    RowState s0 = {0.0f, 0.0f, 0};
    RowState s1 = {0.0f, 0.0f, 0};

    // interleave: compute one segment, then issue the load that replaces it
    compute_seg(a3, lane, true, nv0, s0, adv_out, ret_out, off0 + 3 * SEG);
    Raw a1 = load_seg(rewards, values, done, off0 + 1 * SEG);
    if (has1) compute_seg(b3, lane, true, nv1, s1, adv_out, ret_out, off1 + 3 * SEG);
    Raw b1 = has1 ? load_seg(rewards, values, done, off1 + 1 * SEG) : Raw{};

    compute_seg(a2, lane, false, nv0, s0, adv_out, ret_out, off0 + 2 * SEG);
    Raw a0 = load_seg(rewards, values, done, off0 + 0 * SEG);
    if (has1) compute_seg(b2, lane, false, nv1, s1, adv_out, ret_out, off1 + 2 * SEG);
    Raw b0 = has1 ? load_seg(rewards, values, done, off1 + 0 * SEG) : Raw{};

    compute_seg(a1, lane, false, nv0, s0, adv_out, ret_out, off0 + 1 * SEG);
    if (has1) compute_seg(b1, lane, false, nv1, s1, adv_out, ret_out, off1 + 1 * SEG);
    compute_seg(a0, lane, false, nv0, s0, adv_out, ret_out, off0 + 0 * SEG);
    if (has1) compute_seg(b0, lane, false, nv1, s1, adv_out, ret_out, off1 + 0 * SEG);
}

// Fallback for shapes where T != NSEG*SEG: one thread per row, sequential.
__global__ void gae_naive_kernel(
    const float* __restrict__ rewards,
    const float* __restrict__ values,
    const float* __restrict__ next_value,
    const int*   __restrict__ done,
    float* __restrict__ adv_out,
    float* __restrict__ ret_out,
    int B, int T)
{
    int row = blockIdx.x * blockDim.x + threadIdx.x;
    if (row >= B) return;
    long base = (long)row * T;
    float g = 0.0f;
    for (int t = T - 1; t >= 0; --t) {
        int dcol = (t + 1 < T) ? (t + 1) : (T - 1);
        float nnt = 1.0f - (float)done[base + dcol];
        float nv  = (t + 1 < T) ? values[base + t + 1] : next_value[row];
        float dl  = rewards[base + t] + GAMMA * nv * nnt - values[base + t];
        g = dl + (GAMMA * LAM) * nnt * g;
        adv_out[base + t] = g;
        ret_out[base + t] = g + values[base + t];
    }
}

extern "C" void kernel_launch(void* const* d_in, const int* in_sizes, int n_in,
                              void* d_out, int out_size, void* d_ws, size_t ws_size,
                              hipStream_t stream) {
    const float* rewards    = (const float*)d_in[0];
    const float* values     = (const float*)d_in[1];
    const float* next_value = (const float*)d_in[2];
    const int*   done       = (const int*)d_in[3];

    const int B = in_sizes[2];               // next_value is [B]
    const int T = in_sizes[0] / B;           // rewards is [B, T]

    float* adv = (float*)d_out;
    float* ret = adv + (long)B * T;

    if (T == NSEG * SEG) {
        const int nwaves = (B + RPW - 1) / RPW;       // one wave per 2 rows
        const int grid   = (nwaves + 3) / 4;          // 4 waves per block
        gae_wave2_kernel<<<grid, 256, 0, stream>>>(
            rewards, values, next_value, done, adv, ret, B, T);
    } else {
        gae_naive_kernel<<<(B + 255) / 256, 256, 0, stream>>>(
            rewards, values, next_value, done, adv, ret, B, T);
    }
}